// Round 4
// baseline (60.179 us; speedup 1.0000x reference)
//
#include <hip/hip_runtime.h>
#include <hip/hip_bf16.h>

// InfoNCE loss, B=8192, D=128, T=0.1.
// sim = normalize(E) @ normalize(E)^T / T; per-row masked exp-sums; scalar loss.
// Diagonal included in fused sums, subtracted in finalize via prep-computed
// diag[i] = exp2(dot_ii) with identical rounding to sim's operands.
//
// ws layout:
//   pos_part f32[32][8192]  1MB   (fully written by sim)
//   all_part f32[32][8192]  1MB   (fully written by sim)
//   lab32    i32[8192]            (prep)
//   diag     f32[8192]            (prep)
//   lab8p    u8[8192]             (prep; 32-row-group permuted label bytes)
//   fin_s    f32[32], fin_c f32[32] (fin1)
//   Ebf      bf16[8192*128] 2MB   (prep; unit rows)

#define B_ROWS 8192
#define D_DIM 128
#define K_SCALE 14.426950408889634f  // log2(e)/0.1
#define JSPLIT 32
#define JCHUNK (B_ROWS / JSPLIT)  // 256
#define TILE_J 64
#define NT (JCHUNK / TILE_J)  // 4
#define BM 256                // i-rows per block = 4 waves x 64

typedef __attribute__((ext_vector_type(8))) short bf16x8;
typedef __attribute__((ext_vector_type(16))) float f32x16;
typedef __attribute__((ext_vector_type(4))) unsigned int u32x4;
typedef unsigned int u32;
typedef unsigned long long u64;

static __device__ __forceinline__ unsigned short bf16_bits(float x) {
  __hip_bfloat16 h = __float2bfloat16(x);
  unsigned short u;
  __builtin_memcpy(&u, &h, 2);
  return u;
}
static __device__ __forceinline__ float f32_from_bits(u32 b) {
  float f;
  __builtin_memcpy(&f, &b, 4);
  return f;
}
static __device__ __forceinline__ float bf16f(unsigned short u) {
  return f32_from_bits((u32)u << 16);
}

// Normalize rows in fp32, emit unit bf16 matrix, labels (i32 + permuted u8),
// and diag[i] mirroring sim_kernel's scaled-operand rounding exactly.
__global__ __launch_bounds__(256) void prep_kernel(
    const float* __restrict__ E, const long long* __restrict__ labels,
    __hip_bfloat16* __restrict__ Ebf, int* __restrict__ lab32,
    unsigned char* __restrict__ lab8p, float* __restrict__ diag) {
  const int wid = threadIdx.x >> 6, lane = threadIdx.x & 63;
  const int row = blockIdx.x * 4 + wid;
  const float2 v = *(const float2*)(E + (u64)row * D_DIM + lane * 2);
  float ss = v.x * v.x + v.y * v.y;
#pragma unroll
  for (int m = 1; m < 64; m <<= 1) ss += __shfl_xor(ss, m);
  const float scale = 1.0f / fmaxf(sqrtf(ss), 1e-12f);
  const unsigned short bx = bf16_bits(v.x * scale);
  const unsigned short by = bf16_bits(v.y * scale);
  ((u32*)Ebf)[(u64)row * (D_DIM / 2) + lane] = ((u32)by << 16) | bx;
  const float fx = bf16f(bx), fy = bf16f(by);
  const float ax = bf16f(bf16_bits(fx * K_SCALE));
  const float ay = bf16f(bf16_bits(fy * K_SCALE));
  float dot = ax * fx + ay * fy;
#pragma unroll
  for (int m = 1; m < 64; m <<= 1) dot += __shfl_xor(dot, m);
  if (lane == 0) diag[row] = __builtin_amdgcn_exp2f(dot);

  const int gtid = blockIdx.x * 256 + threadIdx.x;
  if (gtid < B_ROWS) {
    const int lab = (int)labels[gtid];
    lab32[gtid] = lab;
    // permute within 32-row group so reg r / hi-half reads byte h*16+r
    const int local = gtid & 31;
    const int h = (local >> 2) & 1;
    const int r = (local & 3) + 4 * (local >> 3);
    lab8p[(gtid & ~31) + h * 16 + r] = (unsigned char)lab;
  }
}

// Fused sim + exp + masked row partial sums.
// 4 waves; wave w owns 64 i-rows (2 register ifrag sets) at bx*256 + w*64.
// 32x32x16 MFMA, swapped operands D[j][i] = mfma(jfrag_lds, ifrag_reg):
// i = lane&31, j = (r&3)+8*(r>>2)+4*(lane>>5).
// Each ds_read_b128 jfrag feeds TWO MFMAs (acc0/acc1) -> LDS reads halved.
// grid = (32, JSPLIT); per-js partial sums written non-atomically.
__global__ __launch_bounds__(256, 4) void sim_kernel(
    const __hip_bfloat16* __restrict__ Ebf, const int* __restrict__ lab32,
    const unsigned char* __restrict__ lab8p, float* __restrict__ pos_part,
    float* __restrict__ all_part) {
  __shared__ __align__(16) unsigned char lds[2][TILE_J * 256];

  const int t = threadIdx.x;
  const int wid = t >> 6, lane = t & 63;
  const int l31 = lane & 31, hi = lane >> 5;
  const int i0w = blockIdx.x * BM + wid * 64;
  const int jbase0 = blockIdx.y * JCHUNK;

  // two register-resident i-side fragment sets, scaled by K_SCALE
  bf16x8 ifragA[8], ifragB[8];
#pragma unroll
  for (int iset = 0; iset < 2; ++iset) {
    const __hip_bfloat16* src =
        Ebf + (u64)(i0w + iset * 32 + l31) * D_DIM + hi * 8;
#pragma unroll
    for (int ks = 0; ks < 8; ++ks) {
      bf16x8 raw = *(const bf16x8*)(src + ks * 16);
      bf16x8 s;
#pragma unroll
      for (int e = 0; e < 8; ++e)
        s[e] = (short)bf16_bits(bf16f((unsigned short)raw[e]) * K_SCALE);
      if (iset == 0)
        ifragA[ks] = s;
      else
        ifragB[ks] = s;
    }
  }
  const int labi0 = lab32[i0w + l31];
  const int labi1 = lab32[i0w + 32 + l31];

  // swizzled LDS read addressing, folded to 2 registers:
  // offset = l31*256 + ((slot ^ key)<<4), slot = 2*ks + hi, key = lane&15
  const u32 key = lane & 15;
  const u32 M = (key & 14) << 4;
  const u32 base2 = (u32)(l31 * 256) + (((hi ^ (key & 1)) & 1) << 4);

  // staging: wave w stages LDS rows w*16+i*4+(l>>4) linearly; global slot
  // pre-swizzled: slot_g = (l&15) ^ (i*4 + (l>>4))   [m173 pattern]
  const unsigned char* gsrc[4];
  {
    const unsigned char* gb = (const unsigned char*)Ebf;
    const int l4 = lane >> 4, sl = lane & 15;
#pragma unroll
    for (int i = 0; i < 4; ++i) {
      const int rloc = wid * 16 + i * 4 + l4;
      gsrc[i] =
          gb + (u64)(jbase0 + rloc) * 256 + (u64)((sl ^ (i * 4 + l4)) * 16);
    }
  }

  auto stage = [&](int buf) {
#pragma unroll
    for (int i = 0; i < 4; ++i) {
      __builtin_amdgcn_global_load_lds(
          (const __attribute__((address_space(1))) u32*)(gsrc[i]),
          (__attribute__((address_space(3)))
               u32*)(&lds[buf][wid * 4096 + i * 1024]),
          16, 0, 0);
      gsrc[i] += TILE_J * 256;
    }
  };

  float pos0 = 0.f, pos1 = 0.f, all0 = 0.f, all1 = 0.f;

  stage(0);
  __syncthreads();

  for (int tile = 0; tile < NT; ++tile) {
    const int cur = tile & 1;
    if (tile + 1 < NT) stage(cur ^ 1);
    const int jbase = jbase0 + tile * TILE_J;
    const unsigned char* lbuf = lds[cur];
#pragma unroll
    for (int jsub = 0; jsub < 2; ++jsub) {
      f32x16 acc0 = {}, acc1 = {};
#pragma unroll
      for (int ks = 0; ks < 8; ++ks) {
        bf16x8 jfrag = *(const bf16x8*)(lbuf + base2 +
                                        (((u32)(ks << 5)) ^ M) + jsub * 8192);
        acc0 = __builtin_amdgcn_mfma_f32_32x32x16_bf16(jfrag, ifragA[ks], acc0,
                                                       0, 0, 0);
        acc1 = __builtin_amdgcn_mfma_f32_32x32x16_bf16(jfrag, ifragB[ks], acc1,
                                                       0, 0, 0);
      }
      const u32x4 labv = *(const u32x4*)(lab8p + jbase + jsub * 32 + hi * 16);
#pragma unroll
      for (int r = 0; r < 16; ++r) {
        const int labj = (int)((labv[r >> 2] >> ((r & 3) * 8)) & 0xff);
        const float p0 = __builtin_amdgcn_exp2f(acc0[r]);
        const float p1 = __builtin_amdgcn_exp2f(acc1[r]);
        all0 += p0;
        all1 += p1;
        pos0 += (labj == labi0) ? p0 : 0.f;
        pos1 += (labj == labi1) ? p1 : 0.f;
      }
    }
    __syncthreads();
  }

  // lanes l and l+32 hold same i, disjoint j-quarters
  pos0 += __shfl_xor(pos0, 32);
  all0 += __shfl_xor(all0, 32);
  pos1 += __shfl_xor(pos1, 32);
  all1 += __shfl_xor(all1, 32);
  if (hi == 0) {
    const u64 off = (u64)blockIdx.y * B_ROWS;
    pos_part[off + i0w + l31] = pos0;
    all_part[off + i0w + l31] = all0;
    pos_part[off + i0w + 32 + l31] = pos1;
    all_part[off + i0w + 32 + l31] = all1;
  }
}

// Stage 1: per-row reduce of 32 partials, per-block (s,c) partial.
__global__ __launch_bounds__(256) void fin1_kernel(
    const float* __restrict__ pos_part, const float* __restrict__ all_part,
    const float* __restrict__ diag, float* __restrict__ fin_s,
    float* __restrict__ fin_c) {
  const int row = blockIdx.x * 256 + threadIdx.x;
  float ps = 0.f, as_ = 0.f;
#pragma unroll
  for (int js = 0; js < JSPLIT; ++js) {
    ps += pos_part[(u64)js * B_ROWS + row];
    as_ += all_part[(u64)js * B_ROWS + row];
  }
  const float d = diag[row];
  ps -= d;
  as_ -= d;
  float s = 0.f, c = 0.f;
  if (ps > 0.f) {
    s = logf(as_) - logf(ps);
    c = 1.f;
  }
#pragma unroll
  for (int m = 1; m < 64; m <<= 1) {
    s += __shfl_xor(s, m);
    c += __shfl_xor(c, m);
  }
  __shared__ float ls[4], lc[4];
  const int wid = threadIdx.x >> 6, lane = threadIdx.x & 63;
  if (lane == 0) {
    ls[wid] = s;
    lc[wid] = c;
  }
  __syncthreads();
  if (threadIdx.x == 0) {
    fin_s[blockIdx.x] = ls[0] + ls[1] + ls[2] + ls[3];
    fin_c[blockIdx.x] = lc[0] + lc[1] + lc[2] + lc[3];
  }
}

// Stage 2: reduce 32 block partials to the scalar loss.
__global__ __launch_bounds__(64) void fin2_kernel(const float* __restrict__
                                                      fin_s,
                                                  const float* __restrict__
                                                      fin_c,
                                                  float* __restrict__ out) {
  const int lane = threadIdx.x;
  float s = (lane < 32) ? fin_s[lane] : 0.f;
  float c = (lane < 32) ? fin_c[lane] : 0.f;
#pragma unroll
  for (int m = 1; m < 32; m <<= 1) {
    s += __shfl_xor(s, m);
    c += __shfl_xor(c, m);
  }
  if (lane == 0) out[0] = s / fmaxf(c, 1.0f);
}

extern "C" void kernel_launch(void* const* d_in, const int* in_sizes, int n_in,
                              void* d_out, int out_size, void* d_ws,
                              size_t ws_size, hipStream_t stream) {
  const float* E = (const float*)d_in[0];
  const long long* labels = (const long long*)d_in[1];

  float* pos_part = (float*)d_ws;                      // 32*8192
  float* all_part = pos_part + JSPLIT * B_ROWS;        // 32*8192
  int* lab32 = (int*)(all_part + JSPLIT * B_ROWS);     // 8192
  float* diag = (float*)(lab32 + B_ROWS);              // 8192
  unsigned char* lab8p = (unsigned char*)(diag + B_ROWS);  // 8192
  float* fin_s = (float*)(lab8p + B_ROWS);             // 32
  float* fin_c = fin_s + 32;                           // 32
  __hip_bfloat16* Ebf = (__hip_bfloat16*)(fin_c + 32);

  prep_kernel<<<B_ROWS / 4, 256, 0, stream>>>(E, labels, Ebf, lab32, lab8p,
                                              diag);
  sim_kernel<<<dim3(B_ROWS / BM, JSPLIT), 256, 0, stream>>>(
      Ebf, lab32, lab8p, pos_part, all_part);
  fin1_kernel<<<B_ROWS / 256, 256, 0, stream>>>(pos_part, all_part, diag,
                                                fin_s, fin_c);
  fin2_kernel<<<1, 64, 0, stream>>>(fin_s, fin_c, (float*)d_out);
}

// Round 5
// 45.641 us; speedup vs baseline: 1.3185x; 1.3185x over previous
//
#include <hip/hip_runtime.h>
#include <hip/hip_bf16.h>

// InfoNCE loss, B=8192, D=128, T=0.1.
// sim = normalize(E) @ normalize(E)^T / T; per-row masked exp-sums; scalar loss.
// Diagonal included in fused sums, subtracted in finalize via prep-computed
// diag[i] = exp2(dot_ii) with identical rounding to sim's operands.
//
// R5 change vs R4: remove __launch_bounds__(256,4) on sim_kernel — the 128
// VGPR cap forced a scratch spill of the 96-VGPR fragment/acc working set
// (dur 46.5 -> 60.2 regression). Let VGPR float (~160-190), 2-3 blocks/CU.
//
// ws layout:
//   pos_part f32[32][8192]  1MB   (fully written by sim)
//   all_part f32[32][8192]  1MB   (fully written by sim)
//   lab32    i32[8192]            (prep)
//   diag     f32[8192]            (prep)
//   lab8p    u8[8192]             (prep; 32-row-group permuted label bytes)
//   fin_s    f32[32], fin_c f32[32] (fin1)
//   Ebf      bf16[8192*128] 2MB   (prep; unit rows)

#define B_ROWS 8192
#define D_DIM 128
#define K_SCALE 14.426950408889634f  // log2(e)/0.1
#define JSPLIT 32
#define JCHUNK (B_ROWS / JSPLIT)  // 256
#define TILE_J 64
#define NT (JCHUNK / TILE_J)  // 4
#define BM 256                // i-rows per block = 4 waves x 64

typedef __attribute__((ext_vector_type(8))) short bf16x8;
typedef __attribute__((ext_vector_type(16))) float f32x16;
typedef __attribute__((ext_vector_type(4))) unsigned int u32x4;
typedef unsigned int u32;
typedef unsigned long long u64;

static __device__ __forceinline__ unsigned short bf16_bits(float x) {
  __hip_bfloat16 h = __float2bfloat16(x);
  unsigned short u;
  __builtin_memcpy(&u, &h, 2);
  return u;
}
static __device__ __forceinline__ float f32_from_bits(u32 b) {
  float f;
  __builtin_memcpy(&f, &b, 4);
  return f;
}
static __device__ __forceinline__ float bf16f(unsigned short u) {
  return f32_from_bits((u32)u << 16);
}

// Normalize rows in fp32, emit unit bf16 matrix, labels (i32 + permuted u8),
// and diag[i] mirroring sim_kernel's scaled-operand rounding exactly.
__global__ __launch_bounds__(256) void prep_kernel(
    const float* __restrict__ E, const long long* __restrict__ labels,
    __hip_bfloat16* __restrict__ Ebf, int* __restrict__ lab32,
    unsigned char* __restrict__ lab8p, float* __restrict__ diag) {
  const int wid = threadIdx.x >> 6, lane = threadIdx.x & 63;
  const int row = blockIdx.x * 4 + wid;
  const float2 v = *(const float2*)(E + (u64)row * D_DIM + lane * 2);
  float ss = v.x * v.x + v.y * v.y;
#pragma unroll
  for (int m = 1; m < 64; m <<= 1) ss += __shfl_xor(ss, m);
  const float scale = 1.0f / fmaxf(sqrtf(ss), 1e-12f);
  const unsigned short bx = bf16_bits(v.x * scale);
  const unsigned short by = bf16_bits(v.y * scale);
  ((u32*)Ebf)[(u64)row * (D_DIM / 2) + lane] = ((u32)by << 16) | bx;
  const float fx = bf16f(bx), fy = bf16f(by);
  const float ax = bf16f(bf16_bits(fx * K_SCALE));
  const float ay = bf16f(bf16_bits(fy * K_SCALE));
  float dot = ax * fx + ay * fy;
#pragma unroll
  for (int m = 1; m < 64; m <<= 1) dot += __shfl_xor(dot, m);
  if (lane == 0) diag[row] = __builtin_amdgcn_exp2f(dot);

  const int gtid = blockIdx.x * 256 + threadIdx.x;
  if (gtid < B_ROWS) {
    const int lab = (int)labels[gtid];
    lab32[gtid] = lab;
    // permute within 32-row group so reg r / hi-half reads byte h*16+r
    const int local = gtid & 31;
    const int h = (local >> 2) & 1;
    const int r = (local & 3) + 4 * (local >> 3);
    lab8p[(gtid & ~31) + h * 16 + r] = (unsigned char)lab;
  }
}

// Fused sim + exp + masked row partial sums.
// 4 waves; wave w owns 64 i-rows (2 register ifrag sets) at bx*256 + w*64.
// 32x32x16 MFMA, swapped operands D[j][i] = mfma(jfrag_lds, ifrag_reg):
// i = lane&31, j = (r&3)+8*(r>>2)+4*(lane>>5).
// Each ds_read_b128 jfrag feeds TWO MFMAs (acc0/acc1) -> LDS reads halved.
// grid = (32, JSPLIT); per-js partial sums written non-atomically.
__global__ __launch_bounds__(256) void sim_kernel(
    const __hip_bfloat16* __restrict__ Ebf, const int* __restrict__ lab32,
    const unsigned char* __restrict__ lab8p, float* __restrict__ pos_part,
    float* __restrict__ all_part) {
  __shared__ __align__(16) unsigned char lds[2][TILE_J * 256];

  const int t = threadIdx.x;
  const int wid = t >> 6, lane = t & 63;
  const int l31 = lane & 31, hi = lane >> 5;
  const int i0w = blockIdx.x * BM + wid * 64;
  const int jbase0 = blockIdx.y * JCHUNK;

  // two register-resident i-side fragment sets, scaled by K_SCALE
  bf16x8 ifragA[8], ifragB[8];
#pragma unroll
  for (int iset = 0; iset < 2; ++iset) {
    const __hip_bfloat16* src =
        Ebf + (u64)(i0w + iset * 32 + l31) * D_DIM + hi * 8;
#pragma unroll
    for (int ks = 0; ks < 8; ++ks) {
      bf16x8 raw = *(const bf16x8*)(src + ks * 16);
      bf16x8 s;
#pragma unroll
      for (int e = 0; e < 8; ++e)
        s[e] = (short)bf16_bits(bf16f((unsigned short)raw[e]) * K_SCALE);
      if (iset == 0)
        ifragA[ks] = s;
      else
        ifragB[ks] = s;
    }
  }
  const int labi0 = lab32[i0w + l31];
  const int labi1 = lab32[i0w + 32 + l31];

  // swizzled LDS read addressing, folded to 2 registers:
  // offset = l31*256 + ((slot ^ key)<<4), slot = 2*ks + hi, key = lane&15
  const u32 key = lane & 15;
  const u32 M = (key & 14) << 4;
  const u32 base2 = (u32)(l31 * 256) + (((hi ^ (key & 1)) & 1) << 4);

  // staging: wave w stages LDS rows w*16+i*4+(l>>4) linearly; global slot
  // pre-swizzled: slot_g = (l&15) ^ (i*4 + (l>>4))   [m173 pattern]
  const unsigned char* gsrc[4];
  {
    const unsigned char* gb = (const unsigned char*)Ebf;
    const int l4 = lane >> 4, sl = lane & 15;
#pragma unroll
    for (int i = 0; i < 4; ++i) {
      const int rloc = wid * 16 + i * 4 + l4;
      gsrc[i] =
          gb + (u64)(jbase0 + rloc) * 256 + (u64)((sl ^ (i * 4 + l4)) * 16);
    }
  }

  auto stage = [&](int buf) {
#pragma unroll
    for (int i = 0; i < 4; ++i) {
      __builtin_amdgcn_global_load_lds(
          (const __attribute__((address_space(1))) u32*)(gsrc[i]),
          (__attribute__((address_space(3)))
               u32*)(&lds[buf][wid * 4096 + i * 1024]),
          16, 0, 0);
      gsrc[i] += TILE_J * 256;
    }
  };

  float pos0 = 0.f, pos1 = 0.f, all0 = 0.f, all1 = 0.f;

  stage(0);
  __syncthreads();

  for (int tile = 0; tile < NT; ++tile) {
    const int cur = tile & 1;
    if (tile + 1 < NT) stage(cur ^ 1);
    const int jbase = jbase0 + tile * TILE_J;
    const unsigned char* lbuf = lds[cur];
#pragma unroll
    for (int jsub = 0; jsub < 2; ++jsub) {
      f32x16 acc0 = {}, acc1 = {};
#pragma unroll
      for (int ks = 0; ks < 8; ++ks) {
        bf16x8 jfrag = *(const bf16x8*)(lbuf + base2 +
                                        (((u32)(ks << 5)) ^ M) + jsub * 8192);
        acc0 = __builtin_amdgcn_mfma_f32_32x32x16_bf16(jfrag, ifragA[ks], acc0,
                                                       0, 0, 0);
        acc1 = __builtin_amdgcn_mfma_f32_32x32x16_bf16(jfrag, ifragB[ks], acc1,
                                                       0, 0, 0);
      }
      const u32x4 labv = *(const u32x4*)(lab8p + jbase + jsub * 32 + hi * 16);
#pragma unroll
      for (int r = 0; r < 16; ++r) {
        const int labj = (int)((labv[r >> 2] >> ((r & 3) * 8)) & 0xff);
        const float p0 = __builtin_amdgcn_exp2f(acc0[r]);
        const float p1 = __builtin_amdgcn_exp2f(acc1[r]);
        all0 += p0;
        all1 += p1;
        pos0 += (labj == labi0) ? p0 : 0.f;
        pos1 += (labj == labi1) ? p1 : 0.f;
      }
    }
    __syncthreads();
  }

  // lanes l and l+32 hold same i, disjoint j-quarters
  pos0 += __shfl_xor(pos0, 32);
  all0 += __shfl_xor(all0, 32);
  pos1 += __shfl_xor(pos1, 32);
  all1 += __shfl_xor(all1, 32);
  if (hi == 0) {
    const u64 off = (u64)blockIdx.y * B_ROWS;
    pos_part[off + i0w + l31] = pos0;
    all_part[off + i0w + l31] = all0;
    pos_part[off + i0w + 32 + l31] = pos1;
    all_part[off + i0w + 32 + l31] = all1;
  }
}

// Stage 1: per-row reduce of 32 partials, per-block (s,c) partial.
__global__ __launch_bounds__(256) void fin1_kernel(
    const float* __restrict__ pos_part, const float* __restrict__ all_part,
    const float* __restrict__ diag, float* __restrict__ fin_s,
    float* __restrict__ fin_c) {
  const int row = blockIdx.x * 256 + threadIdx.x;
  float ps = 0.f, as_ = 0.f;
#pragma unroll
  for (int js = 0; js < JSPLIT; ++js) {
    ps += pos_part[(u64)js * B_ROWS + row];
    as_ += all_part[(u64)js * B_ROWS + row];
  }
  const float d = diag[row];
  ps -= d;
  as_ -= d;
  float s = 0.f, c = 0.f;
  if (ps > 0.f) {
    s = logf(as_) - logf(ps);
    c = 1.f;
  }
#pragma unroll
  for (int m = 1; m < 64; m <<= 1) {
    s += __shfl_xor(s, m);
    c += __shfl_xor(c, m);
  }
  __shared__ float ls[4], lc[4];
  const int wid = threadIdx.x >> 6, lane = threadIdx.x & 63;
  if (lane == 0) {
    ls[wid] = s;
    lc[wid] = c;
  }
  __syncthreads();
  if (threadIdx.x == 0) {
    fin_s[blockIdx.x] = ls[0] + ls[1] + ls[2] + ls[3];
    fin_c[blockIdx.x] = lc[0] + lc[1] + lc[2] + lc[3];
  }
}

// Stage 2: reduce 32 block partials to the scalar loss.
__global__ __launch_bounds__(64) void fin2_kernel(const float* __restrict__
                                                      fin_s,
                                                  const float* __restrict__
                                                      fin_c,
                                                  float* __restrict__ out) {
  const int lane = threadIdx.x;
  float s = (lane < 32) ? fin_s[lane] : 0.f;
  float c = (lane < 32) ? fin_c[lane] : 0.f;
#pragma unroll
  for (int m = 1; m < 32; m <<= 1) {
    s += __shfl_xor(s, m);
    c += __shfl_xor(c, m);
  }
  if (lane == 0) out[0] = s / fmaxf(c, 1.0f);
}

extern "C" void kernel_launch(void* const* d_in, const int* in_sizes, int n_in,
                              void* d_out, int out_size, void* d_ws,
                              size_t ws_size, hipStream_t stream) {
  const float* E = (const float*)d_in[0];
  const long long* labels = (const long long*)d_in[1];

  float* pos_part = (float*)d_ws;                      // 32*8192
  float* all_part = pos_part + JSPLIT * B_ROWS;        // 32*8192
  int* lab32 = (int*)(all_part + JSPLIT * B_ROWS);     // 8192
  float* diag = (float*)(lab32 + B_ROWS);              // 8192
  unsigned char* lab8p = (unsigned char*)(diag + B_ROWS);  // 8192
  float* fin_s = (float*)(lab8p + B_ROWS);             // 32
  float* fin_c = fin_s + 32;                           // 32
  __hip_bfloat16* Ebf = (__hip_bfloat16*)(fin_c + 32);

  prep_kernel<<<B_ROWS / 4, 256, 0, stream>>>(E, labels, Ebf, lab32, lab8p,
                                              diag);
  sim_kernel<<<dim3(B_ROWS / BM, JSPLIT), 256, 0, stream>>>(
      Ebf, lab32, lab8p, pos_part, all_part);
  fin1_kernel<<<B_ROWS / 256, 256, 0, stream>>>(pos_part, all_part, diag,
                                                fin_s, fin_c);
  fin2_kernel<<<1, 64, 0, stream>>>(fin_s, fin_c, (float*)d_out);
}